// Round 10
// baseline (583.729 us; speedup 1.0000x reference)
//
#include <hip/hip_runtime.h>
#include <hip/hip_bf16.h>
#include <math.h>

#define N_NODES  8192
#define N_EDGES  49152
#define E_TOT    57344   // edges + self-loops
#define IN_F     128
#define HID      64
#define NH1      64
#define NH2      5
#define OUT_F    32
#define F1       4096    // NH1*HID
#define F2       160     // NH2*OUT_F
#define N_BONDS  64
#define KS2      2       // gemm2 k-split (partial buffers)
#define CH       2       // heads per fuse1 block

typedef short bf16x8 __attribute__((ext_vector_type(8)));
typedef float f32x4  __attribute__((ext_vector_type(4)));

__device__ __forceinline__ float lrelu(float x){ return x > 0.f ? x : 0.2f*x; }

__device__ __forceinline__ unsigned short bf16_rne(float f){
    unsigned u = __float_as_uint(f);
    unsigned r = u + 0x7FFF + ((u >> 16) & 1);
    return (unsigned short)(r >> 16);
}
__device__ __forceinline__ float bf16f(unsigned short h){
    return __uint_as_float((unsigned)h << 16);
}

// ---------------- CSR build (sort edges by dst) ----------------
__global__ void k_init_counts(int* counts){
    int i = blockIdx.x*256 + threadIdx.x;
    if (i < N_NODES) counts[i] = 1;   // self-loop
}
__global__ void k_count(const int* __restrict__ ei, int* counts){
    int i = blockIdx.x*256 + threadIdx.x;
    if (i < N_EDGES) atomicAdd(&counts[ei[N_EDGES + i]], 1);
}
__global__ __launch_bounds__(1024) void k_scan(const int* __restrict__ counts,
                                               int* __restrict__ row_start,
                                               int* __restrict__ cursor){
    __shared__ int sd[1024];
    int t = threadIdx.x;
    int v[8]; int sum = 0;
    #pragma unroll
    for (int i=0;i<8;i++){ v[i] = counts[t*8+i]; sum += v[i]; }
    sd[t] = sum; __syncthreads();
    for (int off=1; off<1024; off<<=1){
        int vv = (t >= off) ? sd[t-off] : 0;
        __syncthreads();
        sd[t] += vv;
        __syncthreads();
    }
    int run = sd[t] - sum;  // exclusive prefix
    #pragma unroll
    for (int i=0;i<8;i++){ row_start[t*8+i] = run; cursor[t*8+i] = run; run += v[i]; }
    if (t == 1023) row_start[N_NODES] = run;
}
__global__ void k_fill(const int* __restrict__ ei, int* cursor, int* __restrict__ csr_src){
    int i = blockIdx.x*256 + threadIdx.x;
    if (i >= E_TOT) return;
    int s, d;
    if (i < N_EDGES){ s = ei[i]; d = ei[N_EDGES + i]; }
    else { s = i - N_EDGES; d = s; }
    int pos = atomicAdd(&cursor[d], 1);
    csr_src[pos] = s;
}

// ---------------- split fp32 -> bf16 hi/lo planes ----------------
__global__ void k_split(const float* __restrict__ in, unsigned short* __restrict__ hi,
                        unsigned short* __restrict__ lo, int n){
    int i = blockIdx.x*256 + threadIdx.x;
    if (i < n){
        float f = in[i];
        unsigned short h = bf16_rne(f);
        hi[i] = h;
        lo[i] = bf16_rne(f - bf16f(h));
    }
}

// ------- attention vectors: vsT[k][h] = sum_c a_s[h,c] * W1[h*64+c, k] -------
__global__ __launch_bounds__(128) void k_attvec(const float* __restrict__ W1,
        const float* __restrict__ a_s, const float* __restrict__ a_d,
        float* __restrict__ vsT, float* __restrict__ vdT){
    int h = blockIdx.x, k = threadIdx.x;
    float s = 0.f, d = 0.f;
    for (int c = 0; c < HID; c++){
        float w = W1[(size_t)(h*HID + c)*IN_F + k];
        s += a_s[h*HID + c] * w;
        d += a_d[h*HID + c] * w;
    }
    vsT[k*NH1 + h] = s;
    vdT[k*NH1 + h] = d;
}

// ---------- alpha dots from x: as1[n,h] = x[n,:] . vsT[:,h] ------------------
__global__ __launch_bounds__(128) void k_alpha1x(const float* __restrict__ x,
        const float* __restrict__ vsT, const float* __restrict__ vdT,
        float* __restrict__ as1, float* __restrict__ ad1){
    int n = blockIdx.x, t = threadIdx.x;
    __shared__ float xs[IN_F];
    xs[t] = x[(size_t)n*IN_F + t];
    __syncthreads();
    if (t < NH1){
        float s = 0.f, d = 0.f;
        for (int k = 0; k < IN_F; k++){
            float xv = xs[k];
            s += xv * vsT[k*NH1 + t];
            d += xv * vdT[k*NH1 + t];
        }
        as1[n*NH1 + t] = s;
        ad1[n*NH1 + t] = d;
    }
}

// ---------- per-node per-head softmax denominators (once, all 64 heads) ------
__global__ __launch_bounds__(64) void k_dinv(const float* __restrict__ as1,
        const float* __restrict__ ad1, const int* __restrict__ row_start,
        const int* __restrict__ csr_src, float* __restrict__ dinv){
    int n = blockIdx.x, h = threadIdx.x;
    float ad = ad1[n*NH1 + h];
    int e0 = row_start[n], e1 = row_start[n+1];
    float d = 0.f;
    for (int e = e0; e < e1; e++){
        int s = csr_src[e];
        d += expf(lrelu(as1[s*NH1 + h] + ad));
    }
    dinv[n*NH1 + h] = 1.f / d;
}

// ------- FUSED layer 1: gather(x-space) + MFMA proj + bias/ELU -> x1 frags ---
// grid (N/64, NH1/CH); block 256 = 4 waves; wave owns 16 nodes (one gemm2
// m-tile) and CH heads. Lane (q,l16): node l16, k-feats q*8.. per 32-k step.
// Gather accumulates the MFMA A-fragment directly in registers; per head:
// split-bf16 MFMA vs W1_h planes; epilogue repacks C->A-frag via per-wave LDS
// and writes x1 in gemm2 fragment order ((mtile*128+ksg)*512 + lane*8).
__global__ __launch_bounds__(256) void k_fuse1(const float* __restrict__ x,
        const float* __restrict__ as1, const float* __restrict__ ad1,
        const float* __restrict__ dinv,
        const int* __restrict__ row_start, const int* __restrict__ csr_src,
        const unsigned short* __restrict__ w1hi, const unsigned short* __restrict__ w1lo,
        const float* __restrict__ b1,
        unsigned short* __restrict__ x1hf, unsigned short* __restrict__ x1lf){
    __shared__ unsigned short hs[4][16][72];   // 72: 144B rows, 16B-aligned
    __shared__ unsigned short ls[4][16][72];
    int wave = threadIdx.x >> 6, lane = threadIdx.x & 63;
    int q = lane >> 4, l16 = lane & 15;
    int n = blockIdx.x*64 + wave*16 + l16;
    int h0 = blockIdx.y*CH;
    int mtile = blockIdx.x*4 + wave;
    float acc[CH][4][8] = {};
    int e0 = row_start[n], e1 = row_start[n+1];
    float2 adv = *(const float2*)(ad1 + n*NH1 + h0);
    float2 dvv = *(const float2*)(dinv + n*NH1 + h0);
    float ad[CH] = {adv.x, adv.y};
    float dv[CH] = {dvv.x, dvv.y};
    for (int e = e0; e < e1; e++){
        int s = csr_src[e];
        float2 a12 = *(const float2*)(as1 + s*NH1 + h0);
        float w[CH] = { expf(lrelu(a12.x + ad[0])) * dv[0],
                        expf(lrelu(a12.y + ad[1])) * dv[1] };
        const float* xr = x + (size_t)s*IN_F + q*8;
        #pragma unroll
        for (int ks=0; ks<4; ks++){
            float4 v0 = *(const float4*)(xr + ks*32);
            float4 v1 = *(const float4*)(xr + ks*32 + 4);
            float xv[8] = {v0.x,v0.y,v0.z,v0.w,v1.x,v1.y,v1.z,v1.w};
            #pragma unroll
            for (int c=0;c<CH;c++)
                #pragma unroll
                for (int j=0;j<8;j++) acc[c][ks][j] += w[c]*xv[j];
        }
    }
    #pragma unroll
    for (int c=0;c<CH;c++){
        int hg = h0 + c;
        // split gathered A-fragments
        bf16x8 ah[4], al[4];
        #pragma unroll
        for (int ks=0;ks<4;ks++)
            #pragma unroll
            for (int j=0;j<8;j++){
                float f = acc[c][ks][j];
                unsigned short hb = bf16_rne(f);
                ah[ks][j] = (short)hb;
                al[ks][j] = (short)bf16_rne(f - bf16f(hb));
            }
        // MFMA vs W1_h (B planes L2-hot)
        f32x4 cacc[4] = {};
        #pragma unroll
        for (int ks=0;ks<4;ks++)
            #pragma unroll
            for (int ni=0;ni<4;ni++){
                size_t r = (size_t)(hg*64 + ni*16 + l16)*IN_F + ks*32 + q*8;
                bf16x8 bh = *(const bf16x8*)(w1hi + r);
                bf16x8 bl = *(const bf16x8*)(w1lo + r);
                cacc[ni] = __builtin_amdgcn_mfma_f32_16x16x32_bf16(ah[ks], bh, cacc[ni], 0,0,0);
                cacc[ni] = __builtin_amdgcn_mfma_f32_16x16x32_bf16(ah[ks], bl, cacc[ni], 0,0,0);
                cacc[ni] = __builtin_amdgcn_mfma_f32_16x16x32_bf16(al[ks], bh, cacc[ni], 0,0,0);
            }
        // bias + ELU + split into per-wave LDS tile (C layout: row=q*4+i, col=ni*16+l16)
        #pragma unroll
        for (int ni=0;ni<4;ni++){
            float b = b1[hg*64 + ni*16 + l16];
            #pragma unroll
            for (int i=0;i<4;i++){
                float v = cacc[ni][i] + b;
                float o = v > 0.f ? v : expm1f(v);
                unsigned short hb = bf16_rne(o);
                hs[wave][q*4+i][ni*16 + l16] = hb;
                ls[wave][q*4+i][ni*16 + l16] = bf16_rne(o - bf16f(hb));
            }
        }
        __syncthreads();
        // LDS -> fragment-order global write (A-frag: m=l16, k=ksl*32+q*8+j)
        #pragma unroll
        for (int ksl=0; ksl<2; ksl++){
            bf16x8 fh = *(const bf16x8*)&hs[wave][l16][ksl*32 + q*8];
            bf16x8 fl = *(const bf16x8*)&ls[wave][l16][ksl*32 + q*8];
            int ksg = hg*2 + ksl;
            size_t o = ((size_t)mtile*128 + ksg)*512 + lane*8;
            *(bf16x8*)(x1hf + o) = fh;
            *(bf16x8*)(x1lf + o) = fl;
        }
        __syncthreads();
    }
}

// ------- GEMM2 (MFMA split-bf16, fragment-packed A): part[ks2] = x1 @ W2^T ---
// grid (256, KS2); block 256 = 4 waves (2 m-tiles x 2 n-halves of 80).
// A loads are lane-contiguous 1KB fragment streams (DRAM-friendly);
// B (w2 planes, 2.6 MB) L2-hot. Direct store to own partial (no RMW).
__global__ __launch_bounds__(256) void k_gemm2(
        const unsigned short* __restrict__ x1hf, const unsigned short* __restrict__ x1lf,
        const unsigned short* __restrict__ w2hi, const unsigned short* __restrict__ w2lo,
        float* __restrict__ P){
    int wave = threadIdx.x >> 6, lane = threadIdx.x & 63;
    int wm = wave & 1, wn = wave >> 1;
    int q = lane >> 4, l16 = lane & 15;
    int mtile = blockIdx.x*2 + wm;
    int ks2 = blockIdx.y;
    int ks0 = ks2 * (128/KS2);
    const int nk = 128/KS2;
    const unsigned short* Ah = x1hf + ((size_t)mtile*128 + ks0)*512 + lane*8;
    const unsigned short* Al = x1lf + ((size_t)mtile*128 + ks0)*512 + lane*8;
    f32x4 acc[5] = {};
    bf16x8 ah, al, bh[5], bl[5];
    ah = *(const bf16x8*)Ah;
    al = *(const bf16x8*)Al;
    #pragma unroll
    for (int ni=0;ni<5;ni++){
        size_t r = (size_t)(wn*80 + ni*16 + l16)*F1 + ks0*32 + q*8;
        bh[ni] = *(const bf16x8*)(w2hi + r);
        bl[ni] = *(const bf16x8*)(w2lo + r);
    }
    for (int t = 0; t < nk; t++){
        bf16x8 cah = ah, cal = al, cbh[5], cbl[5];
        #pragma unroll
        for (int ni=0;ni<5;ni++){ cbh[ni] = bh[ni]; cbl[ni] = bl[ni]; }
        if (t + 1 < nk){
            ah = *(const bf16x8*)(Ah + (size_t)(t+1)*512);
            al = *(const bf16x8*)(Al + (size_t)(t+1)*512);
            #pragma unroll
            for (int ni=0;ni<5;ni++){
                size_t r = (size_t)(wn*80 + ni*16 + l16)*F1 + (ks0+t+1)*32 + q*8;
                bh[ni] = *(const bf16x8*)(w2hi + r);
                bl[ni] = *(const bf16x8*)(w2lo + r);
            }
        }
        #pragma unroll
        for (int ni=0;ni<5;ni++){
            acc[ni] = __builtin_amdgcn_mfma_f32_16x16x32_bf16(cah, cbh[ni], acc[ni], 0,0,0);
            acc[ni] = __builtin_amdgcn_mfma_f32_16x16x32_bf16(cah, cbl[ni], acc[ni], 0,0,0);
            acc[ni] = __builtin_amdgcn_mfma_f32_16x16x32_bf16(cal, cbh[ni], acc[ni], 0,0,0);
        }
    }
    float* outp = P + (size_t)ks2 * N_NODES * F2;
    #pragma unroll
    for (int ni=0;ni<5;ni++)
        #pragma unroll
        for (int i=0;i<4;i++)
            outp[(size_t)(mtile*16 + q*4 + i)*F2 + wn*80 + ni*16 + l16] = acc[ni][i];
}

// ---------------- reduce KS2 partials -> h2 ----------------
__global__ __launch_bounds__(256) void k_reduce(const float* __restrict__ P,
                                                float* __restrict__ h2){
    const int NV = N_NODES*F2/4;
    int i = blockIdx.x*256 + threadIdx.x;
    float4 a = ((const float4*)P)[i];
    #pragma unroll
    for (int kb = 1; kb < KS2; kb++){
        float4 b = ((const float4*)P)[(size_t)kb*NV + i];
        a.x += b.x; a.y += b.y; a.z += b.z; a.w += b.w;
    }
    ((float4*)h2)[i] = a;
}

// ---------------- attention dots, layer 2 ----------------
__global__ __launch_bounds__(64) void k_alpha2(const float* __restrict__ h2,
        const float* __restrict__ att_s, const float* __restrict__ att_d,
        float* __restrict__ as2, float* __restrict__ ad2){
    int n = blockIdx.x, t = threadIdx.x;
    float ps = 0.f, pd = 0.f;
    if (t < 40){
        float4 h = *(const float4*)(h2 + (size_t)n*F2 + t*4);
        float4 a = ((const float4*)att_s)[t];
        float4 d = ((const float4*)att_d)[t];
        ps = h.x*a.x + h.y*a.y + h.z*a.z + h.w*a.w;
        pd = h.x*d.x + h.y*d.y + h.z*d.z + h.w*d.w;
    }
    ps += __shfl_xor(ps,1); ps += __shfl_xor(ps,2); ps += __shfl_xor(ps,4);
    pd += __shfl_xor(pd,1); pd += __shfl_xor(pd,2); pd += __shfl_xor(pd,4);
    if (t < 40 && (t & 7) == 0){
        as2[n*NH2 + (t>>3)] = ps;
        ad2[n*NH2 + (t>>3)] = pd;
    }
}

// ------- layer-2 softmax + aggregation + head-mean + b2 ----------------------
__global__ __launch_bounds__(256) void k_agg2(const float* __restrict__ h2,
        const float* __restrict__ as2, const float* __restrict__ ad2,
        const int* __restrict__ row_start, const int* __restrict__ csr_src,
        const float* __restrict__ b2, float* __restrict__ x2){
    int n = blockIdx.x, t = threadIdx.x;
    __shared__ float ad_s[NH2], den_s[NH2], sacc[F2];
    int e0 = row_start[n], e1 = row_start[n+1];
    if (t < NH2) ad_s[t] = ad2[n*NH2 + t];
    __syncthreads();
    if (t < NH2){
        float d = 0.f;
        for (int e=e0;e<e1;e++){
            int s = csr_src[e];
            d += expf(lrelu(as2[s*NH2 + t] + ad_s[t]));
        }
        den_s[t] = d;
    }
    __syncthreads();
    if (t < F2){
        int h = t >> 5;
        float adh  = ad_s[h];
        float dinv = 1.f/den_s[h];
        float acc = 0.f;
        for (int e=e0;e<e1;e++){
            int s = csr_src[e];
            float w = expf(lrelu(as2[s*NH2 + h] + adh)) * dinv;
            acc += w * h2[(size_t)s*F2 + t];
        }
        sacc[t] = acc;
    }
    __syncthreads();
    if (t < OUT_F){
        float v = (sacc[t] + sacc[t+32] + sacc[t+64] + sacc[t+96] + sacc[t+128]) * 0.2f + b2[t];
        x2[n*OUT_F + t] = v;
    }
}

// ---------------- bond scores + softmax over 64 bonds ----------------
__global__ __launch_bounds__(64) void k_bond(const float* __restrict__ x2,
        const int* __restrict__ lefts, const int* __restrict__ rights,
        float* __restrict__ out){
    int b = threadIdx.x;
    int L = lefts[b], R = rights[b];
    float s = 0.f;
    #pragma unroll
    for (int c=0;c<OUT_F;c+=4){
        float4 l4 = *(const float4*)(x2 + (size_t)L*OUT_F + c);
        float4 r4 = *(const float4*)(x2 + (size_t)R*OUT_F + c);
        s += l4.x+l4.y+l4.z+l4.w + r4.x+r4.y+r4.z+r4.w;
    }
    float m = s;
    #pragma unroll
    for (int off=1; off<64; off<<=1) m = fmaxf(m, __shfl_xor(m, off));
    float e = expf(s - m);
    float sum = e;
    #pragma unroll
    for (int off=1; off<64; off<<=1) sum += __shfl_xor(sum, off);
    out[b] = e / sum;
}

extern "C" void kernel_launch(void* const* d_in, const int* in_sizes, int n_in,
                              void* d_out, int out_size, void* d_ws, size_t ws_size,
                              hipStream_t stream){
    const float* x      = (const float*)d_in[0];
    const int*   ei     = (const int*)  d_in[1];
    const int*   lefts  = (const int*)  d_in[2];
    const int*   rights = (const int*)  d_in[3];
    const float* W1     = (const float*)d_in[4];
    const float* att_s1 = (const float*)d_in[5];
    const float* att_d1 = (const float*)d_in[6];
    const float* b1     = (const float*)d_in[7];
    const float* W2     = (const float*)d_in[8];
    const float* att_s2 = (const float*)d_in[9];
    const float* att_d2 = (const float*)d_in[10];
    const float* b2     = (const float*)d_in[11];
    float* out = (float*)d_out;

    // fixed layout, ~163 MB (< proven 169.6 MB ws floor)
    char* ws = (char*)d_ws;
    size_t off = 0;
    auto alloc = [&](size_t bytes) -> void* {
        void* p = ws + off;
        off += (bytes + 255) & ~(size_t)255;
        return p;
    };
    unsigned short* x1hf = (unsigned short*)alloc((size_t)N_NODES*F1*2);  // 67 MB frag-packed
    unsigned short* x1lf = (unsigned short*)alloc((size_t)N_NODES*F1*2);  // 67 MB
    float* part   = (float*)alloc((size_t)KS2*N_NODES*F2*4);              // 10.5 MB
    float* h2     = (float*)alloc((size_t)N_NODES*F2*4);
    float* as1    = (float*)alloc((size_t)N_NODES*NH1*4);
    float* ad1    = (float*)alloc((size_t)N_NODES*NH1*4);
    float* dinv   = (float*)alloc((size_t)N_NODES*NH1*4);
    float* as2    = (float*)alloc((size_t)N_NODES*NH2*4);
    float* ad2    = (float*)alloc((size_t)N_NODES*NH2*4);
    float* x2     = (float*)alloc((size_t)N_NODES*OUT_F*4);
    float* vsT    = (float*)alloc((size_t)IN_F*NH1*4);
    float* vdT    = (float*)alloc((size_t)IN_F*NH1*4);
    unsigned short* w1hi = (unsigned short*)alloc((size_t)F1*IN_F*2);
    unsigned short* w1lo = (unsigned short*)alloc((size_t)F1*IN_F*2);
    unsigned short* w2hi = (unsigned short*)alloc((size_t)F2*F1*2);
    unsigned short* w2lo = (unsigned short*)alloc((size_t)F2*F1*2);
    int* counts    = (int*)alloc((size_t)N_NODES*4);
    int* row_start = (int*)alloc((size_t)(N_NODES+1)*4);
    int* cursor    = (int*)alloc((size_t)N_NODES*4);
    int* csr_src   = (int*)alloc((size_t)E_TOT*4);

    // CSR by destination
    k_init_counts<<<32, 256, 0, stream>>>(counts);
    k_count<<<192, 256, 0, stream>>>(ei, counts);
    k_scan<<<1, 1024, 0, stream>>>(counts, row_start, cursor);
    k_fill<<<224, 256, 0, stream>>>(ei, cursor, csr_src);

    // bf16 hi/lo planes for weights
    k_split<<<(F1*IN_F+255)/256, 256, 0, stream>>>(W1, w1hi, w1lo, F1*IN_F);
    k_split<<<(F2*F1+255)/256,   256, 0, stream>>>(W2, w2hi, w2lo, F2*F1);

    // alpha dots + denominators (once, from x)
    k_attvec<<<NH1, 128, 0, stream>>>(W1, att_s1, att_d1, vsT, vdT);
    k_alpha1x<<<N_NODES, 128, 0, stream>>>(x, vsT, vdT, as1, ad1);
    k_dinv<<<N_NODES, 64, 0, stream>>>(as1, ad1, row_start, csr_src, dinv);

    // fused layer 1: gather + project + ELU -> x1 fragment planes (1 dispatch)
    k_fuse1<<<dim3(N_NODES/64, NH1/CH), 256, 0, stream>>>(
        x, as1, ad1, dinv, row_start, csr_src, w1hi, w1lo, b1, x1hf, x1lf);

    // layer-2 projection (1 dispatch) + reduce
    k_gemm2<<<dim3(256, KS2), 256, 0, stream>>>(x1hf, x1lf, w2hi, w2lo, part);
    k_reduce<<<N_NODES*F2/4/256, 256, 0, stream>>>(part, h2);

    k_alpha2<<<N_NODES, 64, 0, stream>>>(h2, att_s2, att_d2, as2, ad2);
    k_agg2<<<N_NODES, 256, 0, stream>>>(h2, as2, ad2, row_start, csr_src, b2, x2);

    k_bond<<<1, 64, 0, stream>>>(x2, lefts, rights, out);
}

// Round 11
// 521.934 us; speedup vs baseline: 1.1184x; 1.1184x over previous
//
#include <hip/hip_runtime.h>
#include <hip/hip_bf16.h>
#include <math.h>

#define N_NODES  8192
#define N_EDGES  49152
#define E_TOT    57344   // edges + self-loops
#define IN_F     128
#define HID      64
#define NH1      64
#define NH2      5
#define OUT_F    32
#define F1       4096    // NH1*HID
#define F2       160     // NH2*OUT_F
#define N_BONDS  64
#define ET       16      // aggx edge-tile
#define KS2      2       // gemm2 k-split (partial buffers)
#define CH       16      // heads per chunk (4 chunks)

typedef short bf16x8 __attribute__((ext_vector_type(8)));
typedef float f32x4  __attribute__((ext_vector_type(4)));

__device__ __forceinline__ float lrelu(float x){ return x > 0.f ? x : 0.2f*x; }

__device__ __forceinline__ unsigned short bf16_rne(float f){
    unsigned u = __float_as_uint(f);
    unsigned r = u + 0x7FFF + ((u >> 16) & 1);
    return (unsigned short)(r >> 16);
}
__device__ __forceinline__ float bf16f(unsigned short h){
    return __uint_as_float((unsigned)h << 16);
}

// ---------------- CSR build (sort edges by dst) ----------------
__global__ void k_init_counts(int* counts){
    int i = blockIdx.x*256 + threadIdx.x;
    if (i < N_NODES) counts[i] = 1;   // self-loop
}
__global__ void k_count(const int* __restrict__ ei, int* counts){
    int i = blockIdx.x*256 + threadIdx.x;
    if (i < N_EDGES) atomicAdd(&counts[ei[N_EDGES + i]], 1);
}
__global__ __launch_bounds__(1024) void k_scan(const int* __restrict__ counts,
                                               int* __restrict__ row_start,
                                               int* __restrict__ cursor){
    __shared__ int sd[1024];
    int t = threadIdx.x;
    int v[8]; int sum = 0;
    #pragma unroll
    for (int i=0;i<8;i++){ v[i] = counts[t*8+i]; sum += v[i]; }
    sd[t] = sum; __syncthreads();
    for (int off=1; off<1024; off<<=1){
        int vv = (t >= off) ? sd[t-off] : 0;
        __syncthreads();
        sd[t] += vv;
        __syncthreads();
    }
    int run = sd[t] - sum;  // exclusive prefix
    #pragma unroll
    for (int i=0;i<8;i++){ row_start[t*8+i] = run; cursor[t*8+i] = run; run += v[i]; }
    if (t == 1023) row_start[N_NODES] = run;
}
__global__ void k_fill(const int* __restrict__ ei, int* cursor, int* __restrict__ csr_src){
    int i = blockIdx.x*256 + threadIdx.x;
    if (i >= E_TOT) return;
    int s, d;
    if (i < N_EDGES){ s = ei[i]; d = ei[N_EDGES + i]; }
    else { s = i - N_EDGES; d = s; }
    int pos = atomicAdd(&cursor[d], 1);
    csr_src[pos] = s;
}

// ---------------- split fp32 -> bf16 hi/lo planes ----------------
__global__ void k_split(const float* __restrict__ in, unsigned short* __restrict__ hi,
                        unsigned short* __restrict__ lo, int n){
    int i = blockIdx.x*256 + threadIdx.x;
    if (i < n){
        float f = in[i];
        unsigned short h = bf16_rne(f);
        hi[i] = h;
        lo[i] = bf16_rne(f - bf16f(h));
    }
}

// ------- attention vectors: vsT[k][h] = sum_c a_s[h,c] * W1[h*64+c, k] -------
__global__ __launch_bounds__(128) void k_attvec(const float* __restrict__ W1,
        const float* __restrict__ a_s, const float* __restrict__ a_d,
        float* __restrict__ vsT, float* __restrict__ vdT){
    int h = blockIdx.x, k = threadIdx.x;
    float s = 0.f, d = 0.f;
    for (int c = 0; c < HID; c++){
        float w = W1[(size_t)(h*HID + c)*IN_F + k];
        s += a_s[h*HID + c] * w;
        d += a_d[h*HID + c] * w;
    }
    vsT[k*NH1 + h] = s;
    vdT[k*NH1 + h] = d;
}

// ---------- alpha dots from x: as1[n,h] = x[n,:] . vsT[:,h] ------------------
__global__ __launch_bounds__(128) void k_alpha1x(const float* __restrict__ x,
        const float* __restrict__ vsT, const float* __restrict__ vdT,
        float* __restrict__ as1, float* __restrict__ ad1){
    int n = blockIdx.x, t = threadIdx.x;
    __shared__ float xs[IN_F];
    xs[t] = x[(size_t)n*IN_F + t];
    __syncthreads();
    if (t < NH1){
        float s = 0.f, d = 0.f;
        for (int k = 0; k < IN_F; k++){
            float xv = xs[k];
            s += xv * vsT[k*NH1 + t];
            d += xv * vdT[k*NH1 + t];
        }
        as1[n*NH1 + t] = s;
        ad1[n*NH1 + t] = d;
    }
}

// ------- x-space aggregation, CH heads, denom fused --------------------------
// Block per dst node, 256 thr: h = t>>4 (16 heads), f0 = (t&15)*8 (8 feats).
// Block-cooperative edge tiles: stage x rows + unnormalized weights in LDS,
// accumulate Sum(u*x) and D = Sum(u) (free: same wt reads), scale by 1/D at end.
// Output: bf16 hi/lo planes [hc][n][128] for k_gemm1h.
__global__ __launch_bounds__(256) void k_aggx2(const float* __restrict__ x,
        const float* __restrict__ as1, const float* __restrict__ ad1,
        const int* __restrict__ row_start, const int* __restrict__ csr_src,
        unsigned short* __restrict__ txhi, unsigned short* __restrict__ txlo,
        int h0){
    int n = blockIdx.x, t = threadIdx.x;
    __shared__ float ad_s[CH];
    __shared__ float wt[ET][CH];
    __shared__ int   st[ET];
    __shared__ float xs[ET][IN_F];
    int e0 = row_start[n], e1 = row_start[n+1];
    if (t < CH) ad_s[t] = ad1[n*NH1 + h0 + t];
    int h = t >> 4, f0 = (t & 15)*8;
    float acc[8] = {};
    float D = 0.f;
    for (int eb = e0; eb < e1; eb += ET){
        int ne = min(ET, e1 - eb);
        if (t < ne) st[t] = csr_src[eb + t];
        __syncthreads();
        for (int idx = t; idx < ne*32; idx += 256){
            int e = idx >> 5, f4 = idx & 31;
            *(float4*)&xs[e][f4*4] = *(const float4*)(x + (size_t)st[e]*IN_F + f4*4);
        }
        for (int idx = t; idx < ne*CH; idx += 256){
            int e = idx >> 4, hh = idx & (CH-1);
            wt[e][hh] = expf(lrelu(as1[st[e]*NH1 + h0 + hh] + ad_s[hh]));
        }
        __syncthreads();
        for (int e = 0; e < ne; e++){
            float w = wt[e][h];
            D += w;
            float4 v0 = *(const float4*)&xs[e][f0];
            float4 v1 = *(const float4*)&xs[e][f0+4];
            acc[0] += w*v0.x; acc[1] += w*v0.y; acc[2] += w*v0.z; acc[3] += w*v0.w;
            acc[4] += w*v1.x; acc[5] += w*v1.y; acc[6] += w*v1.z; acc[7] += w*v1.w;
        }
        __syncthreads();
    }
    float dinv = 1.f / D;
    bf16x8 hv, lv;
    #pragma unroll
    for (int j=0;j<8;j++){
        float f = acc[j] * dinv;
        unsigned short hb = bf16_rne(f);
        hv[j] = (short)hb;
        lv[j] = (short)bf16_rne(f - bf16f(hb));
    }
    size_t o = ((size_t)h*N_NODES + n)*IN_F + f0;
    *(bf16x8*)(txhi + o) = hv;
    *(bf16x8*)(txlo + o) = lv;
}

// ------- per-head GEMM (MFMA split-bf16) + bias/ELU -> x1 FRAGMENT-packed ----
// grid (64, CH); 4 waves 2x2; wave tile 64 rows x 32 cols, K=128.
// Epilogue: LDS repack -> x1 in gemm2 A-fragment order:
//   [mtile(n>>4)][ksg(kc>>5)][lane=((kc>>3)&3)*16+(n&15)][kc&7], kc = hc*64+c.
__global__ __launch_bounds__(256) void k_gemm1h(const unsigned short* __restrict__ txhi,
        const unsigned short* __restrict__ txlo,
        const unsigned short* __restrict__ w1hi,
        const unsigned short* __restrict__ w1lo,
        const float* __restrict__ b1,
        unsigned short* __restrict__ x1fh, unsigned short* __restrict__ x1fl,
        int h0){
    __shared__ unsigned short hs[4][64][36];
    __shared__ unsigned short ls[4][64][36];
    int wave = threadIdx.x >> 6, lane = threadIdx.x & 63;
    int wm = wave & 1, wn = wave >> 1;
    int hc = blockIdx.y;
    int hg = h0 + hc;
    int m0 = blockIdx.x * 128;
    int q = lane >> 4, l16 = lane & 15;
    const unsigned short* Ah = txhi + (size_t)hc*N_NODES*IN_F;
    const unsigned short* Al = txlo + (size_t)hc*N_NODES*IN_F;
    f32x4 acc[4][2] = {};
    #pragma unroll
    for (int ks = 0; ks < 4; ks++){
        int kb = ks*32 + q*8;
        bf16x8 ah[4], al[4], bh[2], bl[2];
        #pragma unroll
        for (int mi=0;mi<4;mi++){
            size_t r = (size_t)(m0 + wm*64 + mi*16 + l16)*IN_F + kb;
            ah[mi] = *(const bf16x8*)(Ah + r);
            al[mi] = *(const bf16x8*)(Al + r);
        }
        #pragma unroll
        for (int ni=0;ni<2;ni++){
            size_t r = (size_t)(hg*64 + wn*32 + ni*16 + l16)*IN_F + kb;
            bh[ni] = *(const bf16x8*)(w1hi + r);
            bl[ni] = *(const bf16x8*)(w1lo + r);
        }
        #pragma unroll
        for (int mi=0;mi<4;mi++)
            #pragma unroll
            for (int ni=0;ni<2;ni++){
                acc[mi][ni] = __builtin_amdgcn_mfma_f32_16x16x32_bf16(ah[mi], bh[ni], acc[mi][ni], 0,0,0);
                acc[mi][ni] = __builtin_amdgcn_mfma_f32_16x16x32_bf16(ah[mi], bl[ni], acc[mi][ni], 0,0,0);
                acc[mi][ni] = __builtin_amdgcn_mfma_f32_16x16x32_bf16(al[mi], bh[ni], acc[mi][ni], 0,0,0);
            }
    }
    // bias + ELU + split -> per-wave LDS tile [64 rows][32 cols]
    #pragma unroll
    for (int mi=0;mi<4;mi++)
        #pragma unroll
        for (int ni=0;ni<2;ni++){
            int c = wn*32 + ni*16 + l16;
            float b = b1[hg*64 + c];
            #pragma unroll
            for (int i=0;i<4;i++){
                float v = acc[mi][ni][i] + b;
                float o = v > 0.f ? v : expm1f(v);
                unsigned short hb = bf16_rne(o);
                int rr = mi*16 + q*4 + i;
                hs[wave][rr][ni*16 + l16] = hb;
                ls[wave][rr][ni*16 + l16] = bf16_rne(o - bf16f(hb));
            }
        }
    __syncthreads();
    // LDS -> fragment-order write (A-frag: m=l16, k-offset q*8+j within ksg)
    int ksg = hc*2 + wn;
    #pragma unroll
    for (int mi=0;mi<4;mi++){
        int mtile = blockIdx.x*8 + wm*4 + mi;
        bf16x8 fh = *(const bf16x8*)&hs[wave][mi*16 + l16][q*8];
        bf16x8 fl = *(const bf16x8*)&ls[wave][mi*16 + l16][q*8];
        size_t o = ((size_t)mtile*32 + ksg)*512 + lane*8;
        *(bf16x8*)(x1fh + o) = fh;
        *(bf16x8*)(x1fl + o) = fl;
    }
}

// ---------------- zero partials ----------------
__global__ void k_zero(float4* p){
    p[blockIdx.x*256 + threadIdx.x] = float4{0.f,0.f,0.f,0.f};
}

// ------- GEMM2 chunk (MFMA split-bf16, fragment-packed A) --------------------
// grid (256, KS2); block 256 = 4 waves (2 m-tiles x 2 n-halves of 80).
// A: lane-contiguous 1KB fragment streams; B (w2 planes) L2-hot.
// RMW accumulate into own partial across chunks (unique ownership).
__global__ __launch_bounds__(256) void k_gemm2c(
        const unsigned short* __restrict__ x1fh, const unsigned short* __restrict__ x1fl,
        const unsigned short* __restrict__ w2hi, const unsigned short* __restrict__ w2lo,
        float* __restrict__ P, int c0){
    int wave = threadIdx.x >> 6, lane = threadIdx.x & 63;
    int wm = wave & 1, wn = wave >> 1;
    int q = lane >> 4, l16 = lane & 15;
    int mtile = blockIdx.x*2 + wm;
    int ks2 = blockIdx.y;
    int ks0 = ks2 * (32/KS2);
    const int nk = 32/KS2;
    const unsigned short* Ah = x1fh + ((size_t)mtile*32 + ks0)*512 + lane*8;
    const unsigned short* Al = x1fl + ((size_t)mtile*32 + ks0)*512 + lane*8;
    f32x4 acc[5] = {};
    bf16x8 ah, al, bh[5], bl[5];
    ah = *(const bf16x8*)Ah;
    al = *(const bf16x8*)Al;
    #pragma unroll
    for (int ni=0;ni<5;ni++){
        size_t r = (size_t)(wn*80 + ni*16 + l16)*F1 + c0 + ks0*32 + q*8;
        bh[ni] = *(const bf16x8*)(w2hi + r);
        bl[ni] = *(const bf16x8*)(w2lo + r);
    }
    for (int t = 0; t < nk; t++){
        bf16x8 cah = ah, cal = al, cbh[5], cbl[5];
        #pragma unroll
        for (int ni=0;ni<5;ni++){ cbh[ni] = bh[ni]; cbl[ni] = bl[ni]; }
        if (t + 1 < nk){
            ah = *(const bf16x8*)(Ah + (size_t)(t+1)*512);
            al = *(const bf16x8*)(Al + (size_t)(t+1)*512);
            #pragma unroll
            for (int ni=0;ni<5;ni++){
                size_t r = (size_t)(wn*80 + ni*16 + l16)*F1 + c0 + (ks0+t+1)*32 + q*8;
                bh[ni] = *(const bf16x8*)(w2hi + r);
                bl[ni] = *(const bf16x8*)(w2lo + r);
            }
        }
        #pragma unroll
        for (int ni=0;ni<5;ni++){
            acc[ni] = __builtin_amdgcn_mfma_f32_16x16x32_bf16(cah, cbh[ni], acc[ni], 0,0,0);
            acc[ni] = __builtin_amdgcn_mfma_f32_16x16x32_bf16(cah, cbl[ni], acc[ni], 0,0,0);
            acc[ni] = __builtin_amdgcn_mfma_f32_16x16x32_bf16(cal, cbh[ni], acc[ni], 0,0,0);
        }
    }
    float* outp = P + (size_t)ks2 * N_NODES * F2;
    #pragma unroll
    for (int ni=0;ni<5;ni++)
        #pragma unroll
        for (int i=0;i<4;i++){
            size_t idx = (size_t)(mtile*16 + q*4 + i)*F2 + wn*80 + ni*16 + l16;
            outp[idx] += acc[ni][i];
        }
}

// ---------------- reduce KS2 partials -> h2 ----------------
__global__ __launch_bounds__(256) void k_reduce(const float* __restrict__ P,
                                                float* __restrict__ h2){
    const int NV = N_NODES*F2/4;
    int i = blockIdx.x*256 + threadIdx.x;
    float4 a = ((const float4*)P)[i];
    #pragma unroll
    for (int kb = 1; kb < KS2; kb++){
        float4 b = ((const float4*)P)[(size_t)kb*NV + i];
        a.x += b.x; a.y += b.y; a.z += b.z; a.w += b.w;
    }
    ((float4*)h2)[i] = a;
}

// ---------------- attention dots, layer 2 ----------------
__global__ __launch_bounds__(64) void k_alpha2(const float* __restrict__ h2,
        const float* __restrict__ att_s, const float* __restrict__ att_d,
        float* __restrict__ as2, float* __restrict__ ad2){
    int n = blockIdx.x, t = threadIdx.x;
    float ps = 0.f, pd = 0.f;
    if (t < 40){
        float4 h = *(const float4*)(h2 + (size_t)n*F2 + t*4);
        float4 a = ((const float4*)att_s)[t];
        float4 d = ((const float4*)att_d)[t];
        ps = h.x*a.x + h.y*a.y + h.z*a.z + h.w*a.w;
        pd = h.x*d.x + h.y*d.y + h.z*d.z + h.w*d.w;
    }
    ps += __shfl_xor(ps,1); ps += __shfl_xor(ps,2); ps += __shfl_xor(ps,4);
    pd += __shfl_xor(pd,1); pd += __shfl_xor(pd,2); pd += __shfl_xor(pd,4);
    if (t < 40 && (t & 7) == 0){
        as2[n*NH2 + (t>>3)] = ps;
        ad2[n*NH2 + (t>>3)] = pd;
    }
}

// ------- layer-2 softmax + aggregation + head-mean + b2 ----------------------
__global__ __launch_bounds__(256) void k_agg2(const float* __restrict__ h2,
        const float* __restrict__ as2, const float* __restrict__ ad2,
        const int* __restrict__ row_start, const int* __restrict__ csr_src,
        const float* __restrict__ b2, float* __restrict__ x2){
    int n = blockIdx.x, t = threadIdx.x;
    __shared__ float ad_s[NH2], den_s[NH2], sacc[F2];
    int e0 = row_start[n], e1 = row_start[n+1];
    if (t < NH2) ad_s[t] = ad2[n*NH2 + t];
    __syncthreads();
    if (t < NH2){
        float d = 0.f;
        for (int e=e0;e<e1;e++){
            int s = csr_src[e];
            d += expf(lrelu(as2[s*NH2 + t] + ad_s[t]));
        }
        den_s[t] = d;
    }
    __syncthreads();
    if (t < F2){
        int h = t >> 5;
        float adh  = ad_s[h];
        float dinv = 1.f/den_s[h];
        float acc = 0.f;
        for (int e=e0;e<e1;e++){
            int s = csr_src[e];
            float w = expf(lrelu(as2[s*NH2 + h] + adh)) * dinv;
            acc += w * h2[(size_t)s*F2 + t];
        }
        sacc[t] = acc;
    }
    __syncthreads();
    if (t < OUT_F){
        float v = (sacc[t] + sacc[t+32] + sacc[t+64] + sacc[t+96] + sacc[t+128]) * 0.2f + b2[t];
        x2[n*OUT_F + t] = v;
    }
}

// ---------------- bond scores + softmax over 64 bonds ----------------
__global__ __launch_bounds__(64) void k_bond(const float* __restrict__ x2,
        const int* __restrict__ lefts, const int* __restrict__ rights,
        float* __restrict__ out){
    int b = threadIdx.x;
    int L = lefts[b], R = rights[b];
    float s = 0.f;
    #pragma unroll
    for (int c=0;c<OUT_F;c+=4){
        float4 l4 = *(const float4*)(x2 + (size_t)L*OUT_F + c);
        float4 r4 = *(const float4*)(x2 + (size_t)R*OUT_F + c);
        s += l4.x+l4.y+l4.z+l4.w + r4.x+r4.y+r4.z+r4.w;
    }
    float m = s;
    #pragma unroll
    for (int off=1; off<64; off<<=1) m = fmaxf(m, __shfl_xor(m, off));
    float e = expf(s - m);
    float sum = e;
    #pragma unroll
    for (int off=1; off<64; off<<=1) sum += __shfl_xor(sum, off);
    out[b] = e / sum;
}

extern "C" void kernel_launch(void* const* d_in, const int* in_sizes, int n_in,
                              void* d_out, int out_size, void* d_ws, size_t ws_size,
                              hipStream_t stream){
    const float* x      = (const float*)d_in[0];
    const int*   ei     = (const int*)  d_in[1];
    const int*   lefts  = (const int*)  d_in[2];
    const int*   rights = (const int*)  d_in[3];
    const float* W1     = (const float*)d_in[4];
    const float* att_s1 = (const float*)d_in[5];
    const float* att_d1 = (const float*)d_in[6];
    const float* b1     = (const float*)d_in[7];
    const float* W2     = (const float*)d_in[8];
    const float* att_s2 = (const float*)d_in[9];
    const float* att_d2 = (const float*)d_in[10];
    const float* b2     = (const float*)d_in[11];
    float* out = (float*)d_out;

    // fixed layout ~130 MB (< proven 168 MB workspace floor)
    char* ws = (char*)d_ws;
    size_t off = 0;
    auto alloc = [&](size_t bytes) -> void* {
        void* p = ws + off;
        off += (bytes + 255) & ~(size_t)255;
        return p;
    };
    unsigned short* txhi = (unsigned short*)alloc((size_t)CH*N_NODES*IN_F*2);  // 33.5 MB
    unsigned short* txlo = (unsigned short*)alloc((size_t)CH*N_NODES*IN_F*2);  // 33.5 MB
    unsigned short* x1fh = (unsigned short*)alloc((size_t)N_NODES*CH*HID*2);   // 16.8 MB frag
    unsigned short* x1fl = (unsigned short*)alloc((size_t)N_NODES*CH*HID*2);   // 16.8 MB
    float* part   = (float*)alloc((size_t)KS2*N_NODES*F2*4);                   // 10.5 MB
    float* h2     = (float*)alloc((size_t)N_NODES*F2*4);
    float* as1    = (float*)alloc((size_t)N_NODES*NH1*4);
    float* ad1    = (float*)alloc((size_t)N_NODES*NH1*4);
    float* as2    = (float*)alloc((size_t)N_NODES*NH2*4);
    float* ad2    = (float*)alloc((size_t)N_NODES*NH2*4);
    float* x2     = (float*)alloc((size_t)N_NODES*OUT_F*4);
    float* vsT    = (float*)alloc((size_t)IN_F*NH1*4);
    float* vdT    = (float*)alloc((size_t)IN_F*NH1*4);
    unsigned short* w1hi = (unsigned short*)alloc((size_t)F1*IN_F*2);
    unsigned short* w1lo = (unsigned short*)alloc((size_t)F1*IN_F*2);
    unsigned short* w2hi = (unsigned short*)alloc((size_t)F2*F1*2);
    unsigned short* w2lo = (unsigned short*)alloc((size_t)F2*F1*2);
    int* counts    = (int*)alloc((size_t)N_NODES*4);
    int* row_start = (int*)alloc((size_t)(N_NODES+1)*4);
    int* cursor    = (int*)alloc((size_t)N_NODES*4);
    int* csr_src   = (int*)alloc((size_t)E_TOT*4);

    // CSR by destination
    k_init_counts<<<32, 256, 0, stream>>>(counts);
    k_count<<<192, 256, 0, stream>>>(ei, counts);
    k_scan<<<1, 1024, 0, stream>>>(counts, row_start, cursor);
    k_fill<<<224, 256, 0, stream>>>(ei, cursor, csr_src);

    // bf16 hi/lo planes for weights
    k_split<<<(F1*IN_F+255)/256, 256, 0, stream>>>(W1, w1hi, w1lo, F1*IN_F);
    k_split<<<(F2*F1+255)/256,   256, 0, stream>>>(W2, w2hi, w2lo, F2*F1);

    // alpha dots (once, from x); denominators fused into k_aggx2
    k_attvec<<<NH1, 128, 0, stream>>>(W1, att_s1, att_d1, vsT, vdT);
    k_alpha1x<<<N_NODES, 128, 0, stream>>>(x, vsT, vdT, as1, ad1);

    // zero gemm2 partial accumulators
    k_zero<<<KS2*N_NODES*F2/4/256, 256, 0, stream>>>((float4*)part);

    for (int c = 0; c < NH1/CH; c++){
        int h0 = c * CH;
        k_aggx2<<<N_NODES, 256, 0, stream>>>(
            x, as1, ad1, row_start, csr_src, txhi, txlo, h0);
        k_gemm1h<<<dim3(64, CH), 256, 0, stream>>>(
            txhi, txlo, w1hi, w1lo, b1, x1fh, x1fl, h0);
        k_gemm2c<<<dim3(256, KS2), 256, 0, stream>>>(
            x1fh, x1fl, w2hi, w2lo, part, h0*HID);
    }

    k_reduce<<<N_NODES*F2/4/256, 256, 0, stream>>>(part, h2);
    k_alpha2<<<N_NODES, 64, 0, stream>>>(h2, att_s2, att_d2, as2, ad2);
    k_agg2<<<N_NODES, 256, 0, stream>>>(h2, as2, ad2, row_start, csr_src, b2, x2);

    k_bond<<<1, 64, 0, stream>>>(x2, lefts, rights, out);
}